// Round 1
// baseline (319.640 us; speedup 1.0000x reference)
//
#include <hip/hip_runtime.h>
#include <math.h>

// GCN 2-layer (1->8->1), collapsed + factored + dst-binned.
//
// Math (verified):
//   deg[d]  = #edges into d; dinv = rsqrt(deg+1)            (self-loop)
//   v[i]    = dinv[i]*x[i]                                  (stored fp16)
//   acc1[d] = sum_e v[src[e]]
//   at[i]   = dinv[i]*(acc1[i] + v[i])
//   u[i]    = dinv[i] * sum_j relu(at[i]*W1[j]+b1[j])*W2[j] (stored fp16)
//   out[d]  = dinv[d]*(acc2[d] + u[d]) + b2,  acc2[d] = sum_e u[src[e]]
//
// Round-14: r12/r13 showed the scatter kernels are latency-bound with every
// pipe idle (VALUBusy 4%, HBM 6.5%, MfmaUtil 0) and occupancy capped at 33%
// by the grid itself (NB=489 blocks ~ 1.9/CU). Two rounds of source-level
// ILP tricks failed to move VGPR_Count off 12 (serialized gather chains).
// Fix: buy TLP instead of ILP -- split each bucket across SSPLIT=8
// sub-blocks (grid 489 -> 3912 ~ 15 blocks/CU), each with its own LDS
// window, flushed via global atomicAdd (<=8-way contention, pre-zeroed
// accumulators). Per-node math moves to cheap streaming epilogue kernels.
// Record = ((dst&2047)<<20)|src (requires N <= 2^20; N = 1e6 here).

typedef int vint4 __attribute__((ext_vector_type(4)));

#define HB     512     // bucket table capacity (>= NB = 489)
#define STHR   1024    // sort block size (16 waves)
#define CHUNK  16384   // edges per sort block
#define BSH    11      // bucket shift (2048 nodes/bucket)
#define BMASK  2047
#define NWIN   2048    // nodes per bucket window
#define SSPLIT 8       // sub-blocks per bucket for scatter kernels

// ---- zero workspace region (deg, accA, accB, gcur are contiguous) ----
__global__ void k_zero(int* __restrict__ p, long n) {
    long i = blockIdx.x * (long)blockDim.x + threadIdx.x;
    long stride = (long)gridDim.x * blockDim.x;
    long n4 = n >> 2;
    vint4* p4 = reinterpret_cast<vint4*>(p);
    for (long k = i; k < n4; k += stride) p4[k] = (vint4){0, 0, 0, 0};
    for (long k = (n4 << 2) + i; k < n; k += stride) p[k] = 0;
}

// ---- fused counting sort: one block per 16K-edge chunk (unchanged) ----
__global__ __launch_bounds__(STHR) void k_sort(const int* __restrict__ src,
                                               const int* __restrict__ dst,
                                               int E, int NB, int C,
                                               int* __restrict__ gcur,
                                               int* __restrict__ recs) {
    __shared__ int cnt[HB];            // phase A: counts; phase C: cursors
    __shared__ int off[HB + 4];        // exclusive within-block offsets
    __shared__ int res[HB];            // res2[b] = C*b + gbase[b] - off[b]
    __shared__ int part[STHR];
    __shared__ int stage[CHUNK];       // 64 KB bucket-ordered record staging
    __shared__ unsigned short s2b[CHUNK]; // 32 KB slot -> bucket

    int t = threadIdx.x;
    for (int i = t; i < NB; i += STHR) cnt[i] = 0;
    __syncthreads();

    long s0 = (long)blockIdx.x * CHUNK;
    int end = (int)min((long)CHUNK, (long)E - s0);
    const vint4* pd = reinterpret_cast<const vint4*>(dst + s0);
    const vint4* ps = reinterpret_cast<const vint4*>(src + s0);
    int n4 = end >> 2;

    // ---- phase A: bucket histogram (plain load: keep dst lines in L2) ----
    for (int k = t; k < n4; k += STHR) {
        vint4 d = pd[k];
        atomicAdd(&cnt[((unsigned)d.x) >> BSH], 1);
        atomicAdd(&cnt[((unsigned)d.y) >> BSH], 1);
        atomicAdd(&cnt[((unsigned)d.z) >> BSH], 1);
        atomicAdd(&cnt[((unsigned)d.w) >> BSH], 1);
    }
    for (int k = (n4 << 2) + t; k < end; k += STHR)
        atomicAdd(&cnt[((unsigned)dst[s0 + k]) >> BSH], 1);
    __syncthreads();

    // ---- phase B: block scan (1 bucket/thread; NB <= STHR) + reservation ----
    int c0 = (t < NB) ? cnt[t] : 0;
    part[t] = c0;
    __syncthreads();
    for (int o = 1; o < STHR; o <<= 1) {
        int pv = (t >= o) ? part[t - o] : 0;
        __syncthreads();
        part[t] += pv;
        __syncthreads();
    }
    int base0 = (t > 0) ? part[t - 1] : 0;
    if (t < NB) {
        off[t] = base0;
        cnt[t] = base0;                        // cursor for phase C
        int r0 = c0 ? atomicAdd(&gcur[t], c0) : 0;
        res[t] = t * C + r0 - base0;           // res2
    }
    __syncthreads();

    // ---- phase C: place records into LDS staging (bucket-ordered) ----
    for (int k = t; k < n4; k += STHR) {
        vint4 d = pd[k];
        vint4 s = __builtin_nontemporal_load(ps + k);
        int b, slot;
        b = ((unsigned)d.x) >> BSH; slot = atomicAdd(&cnt[b], 1);
        stage[slot] = ((d.x & BMASK) << 20) | s.x; s2b[slot] = (unsigned short)b;
        b = ((unsigned)d.y) >> BSH; slot = atomicAdd(&cnt[b], 1);
        stage[slot] = ((d.y & BMASK) << 20) | s.y; s2b[slot] = (unsigned short)b;
        b = ((unsigned)d.z) >> BSH; slot = atomicAdd(&cnt[b], 1);
        stage[slot] = ((d.z & BMASK) << 20) | s.z; s2b[slot] = (unsigned short)b;
        b = ((unsigned)d.w) >> BSH; slot = atomicAdd(&cnt[b], 1);
        stage[slot] = ((d.w & BMASK) << 20) | s.w; s2b[slot] = (unsigned short)b;
    }
    for (int k = (n4 << 2) + t; k < end; k += STHR) {
        int d = dst[s0 + k], s = src[s0 + k];
        int b = ((unsigned)d) >> BSH;
        int slot = atomicAdd(&cnt[b], 1);
        stage[slot] = ((d & BMASK) << 20) | s;
        s2b[slot] = (unsigned short)b;
    }
    __syncthreads();

    // ---- phase D: flush; plain store so L2 can merge partial lines ----
    for (int i = t; i < end; i += STHR) {
        int b = s2b[i];
        recs[(long)(res[b] + i)] = stage[i];
    }
}

// ---- deg count, SSPLIT sub-blocks per bucket -> global int atomics ----
__global__ __launch_bounds__(512) void k_deg(const int* __restrict__ recs,
                                             const int* __restrict__ gcur, int C,
                                             int* __restrict__ deg, int N) {
    __shared__ int c[NWIN];
    int t = threadIdx.x;
    int b = blockIdx.x / SSPLIT, s = blockIdx.x % SSPLIT;
#pragma unroll
    for (int j = 0; j < NWIN / 512; ++j) c[t + 512 * j] = 0;
    __syncthreads();
    long lo = (long)b * C;
    int cnt_ = gcur[b];
    int beg = (s == 0) ? 0 : ((int)((long)cnt_ * s / SSPLIT) & ~3);
    int end = (s == SSPLIT - 1) ? cnt_ : ((int)((long)cnt_ * (s + 1) / SSPLIT) & ~3);
    const vint4* p = reinterpret_cast<const vint4*>(recs + lo);
    for (int k = (beg >> 2) + t; k < (end >> 2); k += 512) {
        vint4 r = __builtin_nontemporal_load(p + k);
        atomicAdd(&c[((unsigned)r.x) >> 20], 1);
        atomicAdd(&c[((unsigned)r.y) >> 20], 1);
        atomicAdd(&c[((unsigned)r.z) >> 20], 1);
        atomicAdd(&c[((unsigned)r.w) >> 20], 1);
    }
    for (int k = ((end >> 2) << 2) + t; k < end; k += 512)   // tail: last sub-block only
        atomicAdd(&c[((unsigned)__builtin_nontemporal_load(recs + lo + k)) >> 20], 1);
    __syncthreads();
#pragma unroll
    for (int j = 0; j < NWIN / 512; ++j) {
        int idx = t + 512 * j;
        int cv = c[idx];
        int node = b * NWIN + idx;
        if (cv && node < N) atomicAdd(&deg[node], cv);
    }
}

// ---- epilogue: dinv = rsqrt(deg+1); v = dinv*x (fp16) ----
__global__ void k_dinv(const int* __restrict__ deg, const float* __restrict__ x,
                       float* __restrict__ dinv, _Float16* __restrict__ v, int N) {
    int i = blockIdx.x * blockDim.x + threadIdx.x;
    if (i < N) {
        float di = rsqrtf((float)deg[i] + 1.0f);
        dinv[i] = di;
        v[i] = (_Float16)(di * x[i]);
    }
}

// ---- gather/LDS-scatter, SSPLIT sub-blocks per bucket -> global f32 atomics ----
// Used for both layers (val = v -> gacc = accA; val = u -> gacc = accB).
__global__ __launch_bounds__(512) void k_gs(const int* __restrict__ recs,
                                            const int* __restrict__ gcur, int C,
                                            const _Float16* __restrict__ val,
                                            float* __restrict__ gacc, int N) {
    __shared__ float acc[NWIN];
    int t = threadIdx.x;
    int b = blockIdx.x / SSPLIT, s = blockIdx.x % SSPLIT;
#pragma unroll
    for (int j = 0; j < NWIN / 512; ++j) acc[t + 512 * j] = 0.0f;
    __syncthreads();
    long lo = (long)b * C;
    int cnt_ = gcur[b];
    int beg = (s == 0) ? 0 : ((int)((long)cnt_ * s / SSPLIT) & ~3);
    int end = (s == SSPLIT - 1) ? cnt_ : ((int)((long)cnt_ * (s + 1) / SSPLIT) & ~3);
    const vint4* p = reinterpret_cast<const vint4*>(recs + lo);
    for (int k = (beg >> 2) + t; k < (end >> 2); k += 512) {
        vint4 r = __builtin_nontemporal_load(p + k);
        float a0 = (float)val[r.x & 0xFFFFF];
        float a1 = (float)val[r.y & 0xFFFFF];
        float a2 = (float)val[r.z & 0xFFFFF];
        float a3 = (float)val[r.w & 0xFFFFF];
        atomicAdd(&acc[((unsigned)r.x) >> 20], a0);
        atomicAdd(&acc[((unsigned)r.y) >> 20], a1);
        atomicAdd(&acc[((unsigned)r.z) >> 20], a2);
        atomicAdd(&acc[((unsigned)r.w) >> 20], a3);
    }
    for (int k = ((end >> 2) << 2) + t; k < end; k += 512) {
        int r = __builtin_nontemporal_load(recs + lo + k);
        atomicAdd(&acc[((unsigned)r) >> 20], (float)val[r & 0xFFFFF]);
    }
    __syncthreads();
#pragma unroll
    for (int j = 0; j < NWIN / 512; ++j) {
        int idx = t + 512 * j;
        float av = acc[idx];
        int node = b * NWIN + idx;
        if (av != 0.0f && node < N) atomicAdd(&gacc[node], av);
    }
}

// ---- epilogue layer 1: fused MLP -> u (fp16) ----
__global__ void k_u(const float* __restrict__ gacc, const float* __restrict__ dinv,
                    const _Float16* __restrict__ v,
                    const float* __restrict__ W1, const float* __restrict__ b1,
                    const float* __restrict__ W2,
                    _Float16* __restrict__ u, int N) {
    int i = blockIdx.x * blockDim.x + threadIdx.x;
    if (i < N) {
        float di = dinv[i];
        float at = di * (gacc[i] + (float)v[i]);
        float ss = 0.0f;
#pragma unroll
        for (int jj = 0; jj < 8; ++jj)
            ss += fmaxf(at * W1[jj] + b1[jj], 0.0f) * W2[jj];
        u[i] = (_Float16)(di * ss);
    }
}

// ---- epilogue layer 2: finalize ----
__global__ void k_out(const float* __restrict__ gacc, const float* __restrict__ dinv,
                      const _Float16* __restrict__ u, const float* __restrict__ b2,
                      float* __restrict__ out, int N) {
    int i = blockIdx.x * blockDim.x + threadIdx.x;
    if (i < N)
        out[i] = dinv[i] * (gacc[i] + (float)u[i]) + b2[0];
}

extern "C" void kernel_launch(void* const* d_in, const int* in_sizes, int n_in,
                              void* d_out, int out_size, void* d_ws, size_t ws_size,
                              hipStream_t stream) {
    const float* x  = (const float*)d_in[0];
    const int*   ei = (const int*)d_in[1];   // [2, E] int32
    const float* W1 = (const float*)d_in[2];
    const float* b1 = (const float*)d_in[3];
    const float* W2 = (const float*)d_in[4];
    const float* b2 = (const float*)d_in[5];
    float* out = (float*)d_out;

    int N = in_sizes[0];
    int E = in_sizes[1] / 2;
    const int* src = ei;
    const int* dst = ei + E;

    int NB = (N + BMASK) >> BSH;             // 2048-node buckets (489 for N=1e6)

    // fixed bucket capacity: avg + 8 sigma (Poisson), rounded to 64
    int avg = E / NB;
    int C = avg + 8 * (int)sqrt((double)avg) + 64;
    C = (C + 63) & ~63;
    size_t fixed = 20ul * (size_t)N + sizeof(int) * (size_t)NB;
    size_t maxC = (ws_size - fixed) / (sizeof(int) * (size_t)NB);
    if ((size_t)C > maxC) C = (int)maxC;

    char* w = (char*)d_ws;
    float*    dinv = (float*)w;     w += sizeof(float) * (size_t)N;
    _Float16* v    = (_Float16*)w;  w += sizeof(_Float16) * (size_t)N;
    _Float16* u    = (_Float16*)w;  w += sizeof(_Float16) * (size_t)N;
    int*      deg  = (int*)w;       w += sizeof(int) * (size_t)N;       // zeroed
    float*    accA = (float*)w;     w += sizeof(float) * (size_t)N;     // zeroed
    float*    accB = (float*)w;     w += sizeof(float) * (size_t)N;     // zeroed
    int*      gcur = (int*)w;       w += sizeof(int) * (size_t)NB;      // zeroed
    int*      recs = (int*)w;       // NB * C ints

    int NBLK = (E + CHUNK - 1) / CHUNK;
    long zn = 3L * N + NB;                   // deg, accA, accB, gcur contiguous

    k_zero<<<2048, 256, 0, stream>>>(deg, zn);
    k_sort<<<NBLK, STHR, 0, stream>>>(src, dst, E, NB, C, gcur, recs);
    k_deg <<<NB * SSPLIT, 512, 0, stream>>>(recs, gcur, C, deg, N);
    k_dinv<<<(N + 255) / 256, 256, 0, stream>>>(deg, x, dinv, v, N);
    k_gs  <<<NB * SSPLIT, 512, 0, stream>>>(recs, gcur, C, v, accA, N);
    k_u   <<<(N + 255) / 256, 256, 0, stream>>>(accA, dinv, v, W1, b1, W2, u, N);
    k_gs  <<<NB * SSPLIT, 512, 0, stream>>>(recs, gcur, C, u, accB, N);
    k_out <<<(N + 255) / 256, 256, 0, stream>>>(accB, dinv, u, b2, out, N);
}

// Round 2
// 291.731 us; speedup vs baseline: 1.0957x; 1.0957x over previous
//
#include <hip/hip_runtime.h>
#include <math.h>

// GCN 2-layer (1->8->1), collapsed + factored + dst-binned (zero global atomics
// on the accumulate paths).
//
// Math (verified):
//   deg[d]  = #edges into d; dinv = rsqrt(deg+1)            (self-loop)
//   v[i]    = dinv[i]*x[i]                                  (stored fp16)
//   acc1[d] = sum_e v[src[e]]
//   at[i]   = dinv[i]*(acc1[i] + v[i])
//   u[i]    = dinv[i] * sum_j relu(at[i]*W1[j]+b1[j])*W2[j] (stored fp16)
//   out[d]  = dinv[d]*(acc2[d] + u[d]) + b2,  acc2[d] = sum_e u[src[e]]
//
// Round-15: r14 proved occupancy is NOT the limiter (33->74% occupancy,
// dur 63->70us, VALUBusy still 4%): the scatter kernels are per-wave
// latency chains with MLP~1 (VGPR_Count=12). This round buys MLP, not TLP:
// straight-line BATCH=5 record-quad batches (5 NT loads -> 20 independent
// gathers -> predicated LDS atomics), no ternary-predicated loads (they
// blocked hoisting in r13/r14). Structure reverted to r0: SSPLIT=1, fused
// epilogues, direct stores (r14's global-atomic flush + extra kernels cost
// +40us). __launch_bounds__(512,4) caps VGPR at 128 (2 blocks/CU).
// Record = ((dst&2047)<<20)|src (requires N <= 2^20; N = 1e6 here).

typedef int vint4 __attribute__((ext_vector_type(4)));

#define HB    512     // bucket table capacity (>= NB = 489)
#define STHR  1024    // sort block size (16 waves)
#define CHUNK 16384   // edges per sort block
#define BSH   11      // bucket shift (2048 nodes/bucket)
#define BMASK 2047
#define NWIN  2048    // nodes per bucket window
#define BATCH 5       // record-quads in flight per thread (~10 quads/thread total)

__global__ void k_zero_gcur(int* __restrict__ gcur, int NB) {
    int i = blockIdx.x * blockDim.x + threadIdx.x;
    if (i < NB) gcur[i] = 0;
}

// ---- fused counting sort: one block per 16K-edge chunk (unchanged) ----
__global__ __launch_bounds__(STHR) void k_sort(const int* __restrict__ src,
                                               const int* __restrict__ dst,
                                               int E, int NB, int C,
                                               int* __restrict__ gcur,
                                               int* __restrict__ recs) {
    __shared__ int cnt[HB];            // phase A: counts; phase C: cursors
    __shared__ int off[HB + 4];        // exclusive within-block offsets
    __shared__ int res[HB];            // res2[b] = C*b + gbase[b] - off[b]
    __shared__ int part[STHR];
    __shared__ int stage[CHUNK];       // 64 KB bucket-ordered record staging
    __shared__ unsigned short s2b[CHUNK]; // 32 KB slot -> bucket

    int t = threadIdx.x;
    for (int i = t; i < NB; i += STHR) cnt[i] = 0;
    __syncthreads();

    long s0 = (long)blockIdx.x * CHUNK;
    int end = (int)min((long)CHUNK, (long)E - s0);
    const vint4* pd = reinterpret_cast<const vint4*>(dst + s0);
    const vint4* ps = reinterpret_cast<const vint4*>(src + s0);
    int n4 = end >> 2;

    // ---- phase A: bucket histogram (plain load: keep dst lines in L2) ----
    for (int k = t; k < n4; k += STHR) {
        vint4 d = pd[k];
        atomicAdd(&cnt[((unsigned)d.x) >> BSH], 1);
        atomicAdd(&cnt[((unsigned)d.y) >> BSH], 1);
        atomicAdd(&cnt[((unsigned)d.z) >> BSH], 1);
        atomicAdd(&cnt[((unsigned)d.w) >> BSH], 1);
    }
    for (int k = (n4 << 2) + t; k < end; k += STHR)
        atomicAdd(&cnt[((unsigned)dst[s0 + k]) >> BSH], 1);
    __syncthreads();

    // ---- phase B: block scan (1 bucket/thread; NB <= STHR) + reservation ----
    int c0 = (t < NB) ? cnt[t] : 0;
    part[t] = c0;
    __syncthreads();
    for (int o = 1; o < STHR; o <<= 1) {
        int pv = (t >= o) ? part[t - o] : 0;
        __syncthreads();
        part[t] += pv;
        __syncthreads();
    }
    int base0 = (t > 0) ? part[t - 1] : 0;
    if (t < NB) {
        off[t] = base0;
        cnt[t] = base0;                        // cursor for phase C
        int r0 = c0 ? atomicAdd(&gcur[t], c0) : 0;
        res[t] = t * C + r0 - base0;           // res2
    }
    __syncthreads();

    // ---- phase C: place records into LDS staging (bucket-ordered) ----
    for (int k = t; k < n4; k += STHR) {
        vint4 d = pd[k];
        vint4 s = __builtin_nontemporal_load(ps + k);
        int b, slot;
        b = ((unsigned)d.x) >> BSH; slot = atomicAdd(&cnt[b], 1);
        stage[slot] = ((d.x & BMASK) << 20) | s.x; s2b[slot] = (unsigned short)b;
        b = ((unsigned)d.y) >> BSH; slot = atomicAdd(&cnt[b], 1);
        stage[slot] = ((d.y & BMASK) << 20) | s.y; s2b[slot] = (unsigned short)b;
        b = ((unsigned)d.z) >> BSH; slot = atomicAdd(&cnt[b], 1);
        stage[slot] = ((d.z & BMASK) << 20) | s.z; s2b[slot] = (unsigned short)b;
        b = ((unsigned)d.w) >> BSH; slot = atomicAdd(&cnt[b], 1);
        stage[slot] = ((d.w & BMASK) << 20) | s.w; s2b[slot] = (unsigned short)b;
    }
    for (int k = (n4 << 2) + t; k < end; k += STHR) {
        int d = dst[s0 + k], s = src[s0 + k];
        int b = ((unsigned)d) >> BSH;
        int slot = atomicAdd(&cnt[b], 1);
        stage[slot] = ((d & BMASK) << 20) | s;
        s2b[slot] = (unsigned short)b;
    }
    __syncthreads();

    // ---- phase D: flush; plain store so L2 can merge partial lines ----
    for (int i = t; i < end; i += STHR) {
        int b = s2b[i];
        recs[(long)(res[b] + i)] = stage[i];
    }
}

// ---- per-bucket deg count -> dinv, v(fp16); batched record loads ----
__global__ __launch_bounds__(512, 4) void k_degv(const int* __restrict__ recs,
                                                 const int* __restrict__ gcur, int C,
                                                 const float* __restrict__ x,
                                                 float* __restrict__ dinv,
                                                 _Float16* __restrict__ v, int N) {
    __shared__ int c[NWIN];
    int t = threadIdx.x;
#pragma unroll
    for (int j = 0; j < NWIN / 512; ++j) c[t + 512 * j] = 0;
    __syncthreads();
    long lo = (long)blockIdx.x * C;
    int cnt_ = gcur[blockIdx.x];
    int n4 = cnt_ >> 2;
    const vint4* p = reinterpret_cast<const vint4*>(recs + lo);
    for (int k0 = t; k0 < n4; k0 += 512 * BATCH) {
        vint4 r[BATCH];
#pragma unroll
        for (int i = 0; i < BATCH; ++i) {
            int k = k0 + 512 * i;
            r[i] = __builtin_nontemporal_load(p + (k < n4 ? k : k0));
        }
#pragma unroll
        for (int i = 0; i < BATCH; ++i) {
            if (k0 + 512 * i < n4) {
                atomicAdd(&c[((unsigned)r[i].x) >> 20], 1);
                atomicAdd(&c[((unsigned)r[i].y) >> 20], 1);
                atomicAdd(&c[((unsigned)r[i].z) >> 20], 1);
                atomicAdd(&c[((unsigned)r[i].w) >> 20], 1);
            }
        }
    }
    for (int k = (n4 << 2) + t; k < cnt_; k += 512)
        atomicAdd(&c[((unsigned)__builtin_nontemporal_load(recs + lo + k)) >> 20], 1);
    __syncthreads();
#pragma unroll
    for (int j = 0; j < NWIN / 512; ++j) {
        int idx = t + 512 * j;
        int node = blockIdx.x * NWIN + idx;
        if (node < N) {
            float di = rsqrtf((float)c[idx] + 1.0f);
            dinv[node] = di;
            v[node] = (_Float16)(di * x[node]);
        }
    }
}

// ---- layer-1 gather/LDS-scatter + fused MLP -> u(fp16); batched MLP=20 ----
__global__ __launch_bounds__(512, 4) void k_gs1(const int* __restrict__ recs,
                                                const int* __restrict__ gcur, int C,
                                                const _Float16* __restrict__ v,
                                                const float* __restrict__ dinv,
                                                const float* __restrict__ W1,
                                                const float* __restrict__ b1,
                                                const float* __restrict__ W2,
                                                _Float16* __restrict__ u, int N) {
    __shared__ float acc[NWIN];
    int t = threadIdx.x;
#pragma unroll
    for (int j = 0; j < NWIN / 512; ++j) acc[t + 512 * j] = 0.0f;
    __syncthreads();
    long lo = (long)blockIdx.x * C;
    int cnt_ = gcur[blockIdx.x];
    int n4 = cnt_ >> 2;
    const vint4* p = reinterpret_cast<const vint4*>(recs + lo);
    for (int k0 = t; k0 < n4; k0 += 512 * BATCH) {
        vint4 r[BATCH];
#pragma unroll
        for (int i = 0; i < BATCH; ++i) {
            int k = k0 + 512 * i;
            r[i] = __builtin_nontemporal_load(p + (k < n4 ? k : k0));
        }
        float g[BATCH][4];
#pragma unroll
        for (int i = 0; i < BATCH; ++i) {
            g[i][0] = (float)v[(unsigned)(r[i].x & 0xFFFFF)];
            g[i][1] = (float)v[(unsigned)(r[i].y & 0xFFFFF)];
            g[i][2] = (float)v[(unsigned)(r[i].z & 0xFFFFF)];
            g[i][3] = (float)v[(unsigned)(r[i].w & 0xFFFFF)];
        }
#pragma unroll
        for (int i = 0; i < BATCH; ++i) {
            if (k0 + 512 * i < n4) {
                atomicAdd(&acc[((unsigned)r[i].x) >> 20], g[i][0]);
                atomicAdd(&acc[((unsigned)r[i].y) >> 20], g[i][1]);
                atomicAdd(&acc[((unsigned)r[i].z) >> 20], g[i][2]);
                atomicAdd(&acc[((unsigned)r[i].w) >> 20], g[i][3]);
            }
        }
    }
    for (int k = (n4 << 2) + t; k < cnt_; k += 512) {
        int r = __builtin_nontemporal_load(recs + lo + k);
        atomicAdd(&acc[((unsigned)r) >> 20], (float)v[r & 0xFFFFF]);
    }
    __syncthreads();
#pragma unroll
    for (int j = 0; j < NWIN / 512; ++j) {
        int idx = t + 512 * j;
        int node = blockIdx.x * NWIN + idx;
        if (node < N) {
            float di = dinv[node];
            float at = di * (acc[idx] + (float)v[node]);
            float s = 0.0f;
#pragma unroll
            for (int jj = 0; jj < 8; ++jj)
                s += fmaxf(at * W1[jj] + b1[jj], 0.0f) * W2[jj];
            u[node] = (_Float16)(di * s);
        }
    }
}

// ---- layer-2 gather/LDS-scatter + fused finalize -> out; batched MLP=20 ----
__global__ __launch_bounds__(512, 4) void k_gs2(const int* __restrict__ recs,
                                                const int* __restrict__ gcur, int C,
                                                const _Float16* __restrict__ u,
                                                const float* __restrict__ dinv,
                                                const float* __restrict__ b2,
                                                float* __restrict__ out, int N) {
    __shared__ float acc[NWIN];
    int t = threadIdx.x;
#pragma unroll
    for (int j = 0; j < NWIN / 512; ++j) acc[t + 512 * j] = 0.0f;
    __syncthreads();
    long lo = (long)blockIdx.x * C;
    int cnt_ = gcur[blockIdx.x];
    int n4 = cnt_ >> 2;
    const vint4* p = reinterpret_cast<const vint4*>(recs + lo);
    for (int k0 = t; k0 < n4; k0 += 512 * BATCH) {
        vint4 r[BATCH];
#pragma unroll
        for (int i = 0; i < BATCH; ++i) {
            int k = k0 + 512 * i;
            r[i] = __builtin_nontemporal_load(p + (k < n4 ? k : k0));
        }
        float g[BATCH][4];
#pragma unroll
        for (int i = 0; i < BATCH; ++i) {
            g[i][0] = (float)u[(unsigned)(r[i].x & 0xFFFFF)];
            g[i][1] = (float)u[(unsigned)(r[i].y & 0xFFFFF)];
            g[i][2] = (float)u[(unsigned)(r[i].z & 0xFFFFF)];
            g[i][3] = (float)u[(unsigned)(r[i].w & 0xFFFFF)];
        }
#pragma unroll
        for (int i = 0; i < BATCH; ++i) {
            if (k0 + 512 * i < n4) {
                atomicAdd(&acc[((unsigned)r[i].x) >> 20], g[i][0]);
                atomicAdd(&acc[((unsigned)r[i].y) >> 20], g[i][1]);
                atomicAdd(&acc[((unsigned)r[i].z) >> 20], g[i][2]);
                atomicAdd(&acc[((unsigned)r[i].w) >> 20], g[i][3]);
            }
        }
    }
    for (int k = (n4 << 2) + t; k < cnt_; k += 512) {
        int r = __builtin_nontemporal_load(recs + lo + k);
        atomicAdd(&acc[((unsigned)r) >> 20], (float)u[r & 0xFFFFF]);
    }
    __syncthreads();
#pragma unroll
    for (int j = 0; j < NWIN / 512; ++j) {
        int idx = t + 512 * j;
        int node = blockIdx.x * NWIN + idx;
        if (node < N)
            out[node] = dinv[node] * (acc[idx] + (float)u[node]) + b2[0];
    }
}

extern "C" void kernel_launch(void* const* d_in, const int* in_sizes, int n_in,
                              void* d_out, int out_size, void* d_ws, size_t ws_size,
                              hipStream_t stream) {
    const float* x  = (const float*)d_in[0];
    const int*   ei = (const int*)d_in[1];   // [2, E] int32
    const float* W1 = (const float*)d_in[2];
    const float* b1 = (const float*)d_in[3];
    const float* W2 = (const float*)d_in[4];
    const float* b2 = (const float*)d_in[5];
    float* out = (float*)d_out;

    int N = in_sizes[0];
    int E = in_sizes[1] / 2;
    const int* src = ei;
    const int* dst = ei + E;

    int NB = (N + BMASK) >> BSH;             // 2048-node buckets (489 for N=1e6)

    // fixed bucket capacity: avg + 8 sigma (Poisson), rounded to 64
    int avg = E / NB;
    int C = avg + 8 * (int)sqrt((double)avg) + 64;
    C = (C + 63) & ~63;
    size_t fixed = sizeof(float) * (size_t)N + sizeof(_Float16) * 2ul * N
                 + sizeof(int) * (size_t)NB;
    size_t maxC = (ws_size - fixed) / (sizeof(int) * (size_t)NB);
    if ((size_t)C > maxC) C = (int)maxC;

    char* w = (char*)d_ws;
    float*    dinv = (float*)w;     w += sizeof(float) * (size_t)N;
    _Float16* v    = (_Float16*)w;  w += sizeof(_Float16) * (size_t)N;
    _Float16* u    = (_Float16*)w;  w += sizeof(_Float16) * (size_t)N;
    int*      gcur = (int*)w;       w += sizeof(int) * (size_t)NB;
    int*      recs = (int*)w;       // NB * C ints

    int NBLK = (E + CHUNK - 1) / CHUNK;

    k_zero_gcur<<<(NB + 255) / 256, 256, 0, stream>>>(gcur, NB);
    k_sort<<<NBLK, STHR, 0, stream>>>(src, dst, E, NB, C, gcur, recs);
    k_degv<<<NB, 512, 0, stream>>>(recs, gcur, C, x, dinv, v, N);
    k_gs1 <<<NB, 512, 0, stream>>>(recs, gcur, C, v, dinv, W1, b1, W2, u, N);
    k_gs2 <<<NB, 512, 0, stream>>>(recs, gcur, C, u, dinv, b2, out, N);
}